// Round 3
// baseline (179.657 us; speedup 1.0000x reference)
//
#include <hip/hip_runtime.h>
#include <hip/hip_bf16.h>
#include <math.h>

// Problem constants
#define B_ 4
#define NQ 5440          // 64*64 + 32*32 + 16*16 + 8*8
#define M_ROWS (B_ * NQ) // 21760
#define NH 8
#define NL 4
#define NP 4
#define HD 32

// v layouts (bytes):
//  even plane (natural): per (b,h): 5440 px * 64 B = 348160; pair k = px(2k,2k+1) at k*128
//  odd  plane (shifted): per (b,h): pairs (clamp(2k-1),clamp(2k)), rows of W/2+1 pairs
//    pairs/level: L0 64*33=2112, L1 32*17=544, L2 16*9=144, L3 8*5=40 -> 2840*128=363520
#define EV_PLANE 348160u
#define OD_PLANE 363520u
#define SZ_V_B   11141120u   // M_ROWS*256*2 ; also byte offset v_even -> v_odd
#define SZ_ODD_B 11632640u   // 32 * OD_PLANE

typedef __attribute__((ext_vector_type(8))) short bf16x8; // 8 bf16 (4 VGPRs)
typedef __attribute__((ext_vector_type(4))) short bf16x4; // 8 bytes
typedef __attribute__((ext_vector_type(4))) float f32x4;
typedef _Float16 f16;

static __device__ __forceinline__ unsigned short f2bf(float f) {
  union { float f; unsigned u; } v; v.f = f;
  unsigned r = (v.u + 0x7fffu + ((v.u >> 16) & 1u)) >> 16; // RNE
  return (unsigned short)r;
}
static __device__ __forceinline__ float bits2f(unsigned u) {
  union { unsigned u; float f; } v; v.u = u; return v.f;
}

// ---------------- merged prep: fp32->bf16 of value+query + weight transpose/convert
__global__ __launch_bounds__(256) void prep_all(
    const float* __restrict__ value, const float* __restrict__ query,
    unsigned short* __restrict__ value_bf, unsigned short* __restrict__ query_bf,
    const float* __restrict__ vpw, const float* __restrict__ offw,
    const float* __restrict__ attnw, const float* __restrict__ outw,
    const float* __restrict__ offb, const float* __restrict__ attnb,
    unsigned short* __restrict__ vp_t, unsigned short* __restrict__ q_t,
    unsigned short* __restrict__ out_t, float* __restrict__ biasq, int n4) {
  int id = blockIdx.x * 256 + threadIdx.x;
  if (id < 2 * n4) { // conversion part
    const float* src; unsigned short* dst; int j;
    if (id < n4) { src = value; dst = value_bf; j = id; }
    else { src = query; dst = query_bf; j = id - n4; }
    float4 f = ((const float4*)src)[j];
    bf16x4 o;
    o[0] = (short)f2bf(f.x); o[1] = (short)f2bf(f.y);
    o[2] = (short)f2bf(f.z); o[3] = (short)f2bf(f.w);
    ((bf16x4*)dst)[j] = o;
    return;
  }
  int w = id - 2 * n4;
  if (w < 65536) {                        // vp_t[256][256]
    int n = w >> 8, k = w & 255;
    vp_t[w] = f2bf(vpw[k * 256 + n]);
  } else if (w < 163840) {                // q_t[384][256] = [off^T ; attn^T]
    int q = w - 65536; int n = q >> 8, k = q & 255;
    q_t[q] = f2bf(n < 256 ? offw[k * 256 + n] : attnw[k * 128 + (n - 256)]);
  } else if (w < 229376) {                // out_t[256][256]
    int o = w - 163840; int n = o >> 8, k = o & 255;
    out_t[o] = f2bf(outw[k * 256 + n]);
  } else if (w < 229760) {                // biasq[384]
    int j = w - 229376;
    biasq[j] = j < 256 ? offb[j] : attnb[j - 256];
  }
}

// ---------------- GEMM1+2 merged: B-tile in LDS (1 barrier), ALL 16 A-fragments
// register-prefetched BEFORE the barrier. Block = 128 M x 64 N.
__global__ __launch_bounds__(256) void gemm12_kernel(
    const unsigned short* __restrict__ valbf, const unsigned short* __restrict__ qrybf,
    const unsigned short* __restrict__ wt_vp, const unsigned short* __restrict__ wt_q,
    const float* __restrict__ vp_b, const float* __restrict__ biasq,
    unsigned short* __restrict__ v_bf, f16* __restrict__ offaw_h) {
  __shared__ unsigned short Bs[8 * 64 * 32]; // 32 KB: 8 k-tiles of [64 n][32 k]
  const int t = threadIdx.x;
  const int lane = t & 63, wid = t >> 6;
  const int qd = lane >> 4, l16 = lane & 15;
  const int g = blockIdx.x;
  const int grp = g / 80, r = g % 80;
  int by, bx;
  if (grp < 21) { by = grp * 8 + (r & 7); bx = r >> 3; }
  else          { by = 168 + (r & 1);     bx = r >> 1; } // tail: 2 rows x 10 cols
  const int bm = by * 128;
  const bool isv = bx < 4;
  const int bn = isv ? bx * 64 : (bx - 4) * 64;
  const unsigned short* A  = isv ? valbf : qrybf;
  const unsigned short* Wt = isv ? wt_vp : wt_q;

  // stage B tile (weights) via async global->LDS
  const unsigned short* bg = Wt + (size_t)(bn + (t >> 2)) * 256 + (t & 3) * 8;
  unsigned short* bs_b = Bs + (t & 192) * 8;
#pragma unroll
  for (int j = 0; j < 8; ++j)
    __builtin_amdgcn_global_load_lds(
        (const __attribute__((address_space(1))) void*)(bg + j * 32),
        (__attribute__((address_space(3))) void*)(bs_b + j * 2048), 16, 0, 0);

  // prefetch ALL A fragments into registers (16 independent dwordx4 loads)
  const unsigned short* ar0 = A + (size_t)(bm + wid * 32 + l16) * 256 + qd * 8;
  const unsigned short* ar1 = ar0 + 16 * 256;
  bf16x8 a0[8], a1[8];
#pragma unroll
  for (int j = 0; j < 8; ++j) {
    a0[j] = *(const bf16x8*)(ar0 + j * 32);
    a1[j] = *(const bf16x8*)(ar1 + j * 32);
  }
  __syncthreads(); // drains vmcnt: B staged AND A regs resident

  f32x4 acc[2][4] = {};
#pragma unroll
  for (int j = 0; j < 8; ++j) {
    const unsigned short* bt = Bs + j * 2048 + l16 * 32 + qd * 8;
#pragma unroll
    for (int ni = 0; ni < 4; ++ni) {
      const bf16x8 bf = *(const bf16x8*)(bt + ni * 512);
      acc[0][ni] = __builtin_amdgcn_mfma_f32_16x16x32_bf16(a0[j], bf, acc[0][ni], 0, 0, 0);
      acc[1][ni] = __builtin_amdgcn_mfma_f32_16x16x32_bf16(a1[j], bf, acc[1][ni], 0, 0, 0);
    }
  }
  // C/D layout: col = lane&15, row = (lane>>4)*4 + reg [m89-verified]
  if (isv) {
#pragma unroll
    for (int ni = 0; ni < 4; ++ni) {
      const int c = bn + ni * 16 + l16;
      const float bb = vp_b[c];
      const int h = c >> 5, d = c & 31;
#pragma unroll
      for (int mi = 0; mi < 2; ++mi)
#pragma unroll
        for (int rr = 0; rr < 4; ++rr) {
          const int gm = bm + wid * 32 + mi * 16 + qd * 4 + rr;
          const int b = gm / NQ, pix = gm - b * NQ;
          v_bf[((size_t)(b * NH + h) * NQ + pix) * HD + d] = f2bf(acc[mi][ni][rr] + bb);
        }
    }
  } else {
#pragma unroll
    for (int ni = 0; ni < 4; ++ni) {
      const int c = bn + ni * 16 + l16;
      const float bb = biasq[c];
#pragma unroll
      for (int mi = 0; mi < 2; ++mi)
#pragma unroll
        for (int rr = 0; rr < 4; ++rr) {
          const int gm = bm + wid * 32 + mi * 16 + qd * 4 + rr;
          offaw_h[(size_t)gm * 384 + c] = (f16)(acc[mi][ni][rr] + bb);
        }
    }
  }
}

// ---------------- build the half-pixel-shifted odd-pair copy of v.
// odd plane pair slot k' (0..W/2) of row y holds pixels (clamp(2k'-1), clamp(2k')).
// 2840 pairs * 32 planes; 8 threads per pair (2 half * 4 d8 of 16 B).
__global__ __launch_bounds__(256) void dup_odd_kernel(
    const unsigned short* __restrict__ v_even, unsigned short* __restrict__ v_odd) {
  const int id = blockIdx.x * 256 + threadIdx.x;  // 2840 blocks -> 727040 threads
  const int pairglob = id >> 3;
  const int half = (id >> 2) & 1, d8 = id & 3;
  const int plane = pairglob / 2840;
  const int r = pairglob - plane * 2840;
  int l, row, k, Wl, loff;
  if (r < 2112)      { l = 0; Wl = 64; loff = 0;    const int rr = r;        row = rr / 33; k = rr - row * 33; }
  else if (r < 2656) { l = 1; Wl = 32; loff = 4096; const int rr = r - 2112; row = rr / 17; k = rr - row * 17; }
  else if (r < 2800) { l = 2; Wl = 16; loff = 5120; const int rr = r - 2656; row = rr / 9;  k = rr - row * 9;  }
  else               { l = 3; Wl = 8;  loff = 5376; const int rr = r - 2800; row = rr / 5;  k = rr - row * 5;  }
  (void)l;
  int px = 2 * k - 1 + half; px = min(max(px, 0), Wl - 1);
  const int spix = loff + row * Wl + px;
  const uint4 val = *(const uint4*)((const char*)v_even +
      ((size_t)plane * 5440 + spix) * 64 + d8 * 16);
  *(uint4*)((char*)v_odd + (size_t)plane * OD_PLANE + (size_t)r * 128 +
            half * 64 + d8 * 16) = val;
}

// ---------------- Fused softmax + deformable sampling, full-line gather.
// Phase A picks per sample the layout whose 128 B pair exactly covers (x0,x1):
// parity = x0&1 -> even plane (natural) or odd plane (half-shifted). Emits one
// packed pair index per bilinear row (bit15 = parity) + 4 weights.
// Phase B lane map: qh_lo(2b)|rowpair(1b)|half(1b)|d8(2b) -> each wave inst
// reads 8 fully-aligned, fully-used 128 B lines. L2 line accesses: 2/sample
// (was ~3 partial); internal L2 traffic 713 MB (was ~1.07 GB).
__global__ __launch_bounds__(256) void sample_fused_kernel(
    const unsigned short* __restrict__ v, const float* __restrict__ refp,
    const f16* __restrict__ offaw_h, unsigned short* __restrict__ out) {
  __shared__ __align__(16) unsigned s_idx32[16 * 64];   // 4 KB  [p][qh] -> (i1<<16)|i0
  __shared__ __align__(16) float s_wts[16 * 64 * 4];    // 16 KB [p][qh][rp][half]
  const int t = threadIdx.x;
  // XCD swizzle: xcd = blk&7, batch = xcd>>1
  const int blk = blockIdx.x;
  const int b = (blk & 7) >> 1;
  const int q0loc = ((blk >> 3) * 2 + (blk & 1)) * 8;
  const int q0 = b * NQ + q0loc;

  { // ---- phase A: load offsets+logits, in-wave softmax, pair-tuple compute
    const int lane = t & 63, wave = t >> 6;
    const int qh = wave * 16 + (lane >> 2);     // 64 (q,h) pairs
    const int l = lane & 3;                     // level within 4-lane group
    const int q = qh >> 3, h = qh & 7;
    const f16* row = offaw_h + (size_t)(q0 + q) * 384;
    union { uint4 u4; f16 hh[8]; } off8;
    off8.u4 = *(const uint4*)(row + h * 32 + l * 8);
    union { uint2 u2; f16 hh[4]; } lg4;
    lg4.u2 = *(const uint2*)(row + 256 + h * 16 + l * 4);
    const float2 rxy = *(const float2*)(refp + (size_t)(q0 + q) * 8 + l * 2);

    // softmax over 16 logits spread 4-per-lane across the 4-lane group
    float lgf[4];
#pragma unroll
    for (int j = 0; j < 4; ++j) lgf[j] = (float)lg4.hh[j];
    float m = fmaxf(fmaxf(lgf[0], lgf[1]), fmaxf(lgf[2], lgf[3]));
    m = fmaxf(m, __shfl_xor(m, 1));
    m = fmaxf(m, __shfl_xor(m, 2));
    float e[4], s = 0.f;
#pragma unroll
    for (int j = 0; j < 4; ++j) { e[j] = __expf(lgf[j] - m); s += e[j]; }
    s += __shfl_xor(s, 1);
    s += __shfl_xor(s, 2);
    const float inv = 1.f / s;

    const int Wl = 64 >> l, Hl = 64 >> l, W2 = Wl >> 1;
    // pair-index bases (in 128 B units) within a (b,h) plane
    const int EB = (l == 0) ? 0 : (l == 1) ? 2048 : (l == 2) ? 2560 : 2688;
    const int OB = (l == 0) ? 0 : (l == 1) ? 2112 : (l == 2) ? 2656 : 2800;
    const float pxb = rxy.x * (float)Wl - 0.5f;
    const float pyb = rxy.y * (float)Hl - 0.5f;
#pragma unroll
    for (int pp = 0; pp < 4; ++pp) {
      const int p = l * 4 + pp;
      const float ox = (float)off8.hh[pp * 2];
      const float oy = (float)off8.hh[pp * 2 + 1];
      const float a  = e[pp] * inv;
      const float px = pxb + ox;
      const float py = pyb + oy;
      const float x0f = floorf(px), y0f = floorf(py);
      const int x0 = (int)x0f, y0 = (int)y0f;
      const int x1 = x0 + 1, y1 = y0 + 1;
      const float wx = px - x0f, wy = py - y0f;
      const float m_x0 = (x0 >= 0 && x0 < Wl) ? 1.f : 0.f;
      const float m_x1 = (x1 >= 0 && x1 < Wl) ? 1.f : 0.f;
      const float m_y0 = (y0 >= 0 && y0 < Hl) ? 1.f : 0.f;
      const float m_y1 = (y1 >= 0 && y1 < Hl) ? 1.f : 0.f;
      const int cy0 = min(max(y0, 0), Hl - 1), cy1 = min(max(y1, 0), Hl - 1);
      const int par = x0 & 1;                  // works for negative x0 too
      int col, base, rowp;
      if (par) { col = min(max((x0 + 1) >> 1, 0), W2);     base = OB + 0x8000; rowp = W2 + 1; }
      else     { col = min(max(x0 >> 1, 0), W2 - 1);       base = EB;          rowp = W2; }
      const unsigned i0 = (unsigned)(base + cy0 * rowp + col);
      const unsigned i1 = (unsigned)(base + cy1 * rowp + col);
      const int ti = p * 64 + qh;
      s_idx32[ti] = i0 | (i1 << 16);
      float4 w4;                               // [rp][half] = [y][x]
      w4.x = a * (1.f - wx) * (1.f - wy) * m_x0 * m_y0;
      w4.y = a * wx * (1.f - wy) * m_x1 * m_y0;
      w4.z = a * (1.f - wx) * wy * m_x0 * m_y1;
      w4.w = a * wx * wy * m_x1 * m_y1;
      *(float4*)&s_wts[ti * 4] = w4;
    }
  }
  __syncthreads();
  // ---- phase B: full-line gather. lane = qh_lo(2b)|rp(1b)|half(1b)|d8(2b)
  const int lane = t & 63, wave = t >> 6;
  const int qh_lo = lane >> 4;
  const int rp    = (lane >> 3) & 1;
  const int half  = (lane >> 2) & 1;
  const int d8    = lane & 3;
  const char* vB = (const char*)v;
  const unsigned sub = (unsigned)(half * 64 + d8 * 16);

  for (int s = 0; s < 4; ++s) {
    const int tqh = wave * 16 + s * 4 + qh_lo;
    const int h = tqh & 7;
    const unsigned plane = (unsigned)(b * NH + h);
    const unsigned ebase = plane * EV_PLANE + sub;
    const unsigned obase = SZ_V_B + plane * OD_PLANE + sub;
    float acc[8] = {};
#pragma unroll
    for (int p = 0; p < 16; ++p) {
      const unsigned ip = ((const unsigned short*)s_idx32)[(p * 64 + tqh) * 2 + rp];
      const float w = s_wts[((p * 64 + tqh) * 2 + rp) * 2 + half];
      const unsigned addr = ((ip & 0x8000u) ? obase : ebase) + ((ip & 0x7fffu) << 7);
      union { bf16x8 v8; unsigned u[4]; } cc;
      cc.v8 = *(const bf16x8*)(vB + addr);
#pragma unroll
      for (int k = 0; k < 4; ++k) {
        acc[2 * k]     += w * bits2f(cc.u[k] << 16);
        acc[2 * k + 1] += w * bits2f(cc.u[k] & 0xffff0000u);
      }
    }
    // combine: half (bit2), rowpair (bit3)
#pragma unroll
    for (int k = 0; k < 8; ++k) {
      acc[k] += __shfl_xor(acc[k], 4);
      acc[k] += __shfl_xor(acc[k], 8);
    }
    if ((lane & 12) == 0) {
      const int q = tqh >> 3;
      bf16x8 ov;
#pragma unroll
      for (int k = 0; k < 8; ++k) ov[k] = (short)f2bf(acc[k]);
      *(bf16x8*)(out + (size_t)(q0 + q) * 256 + h * HD + d8 * 8) = ov;
    }
  }
}

// ---------------- GEMM3: out = attn_bf @ out_w^T + out_b (fp32), same A-prefetch
__global__ __launch_bounds__(256) void gemm_out_kernel(
    const unsigned short* __restrict__ attn_bf, const unsigned short* __restrict__ wt_out,
    const float* __restrict__ out_b, float* __restrict__ out) {
  __shared__ unsigned short Bs[8 * 64 * 32];
  const int t = threadIdx.x;
  const int lane = t & 63, wid = t >> 6;
  const int qd = lane >> 4, l16 = lane & 15;
  const int g = blockIdx.x;
  const int grp = g / 32, r = g % 32;
  int by, bx;
  if (grp < 21) { by = grp * 8 + (r & 7); bx = r >> 3; }
  else          { by = 168 + (r & 1);     bx = r >> 1; }
  const int bm = by * 128, bn = bx * 64;

  const unsigned short* bg = wt_out + (size_t)(bn + (t >> 2)) * 256 + (t & 3) * 8;
  unsigned short* bs_b = Bs + (t & 192) * 8;
#pragma unroll
  for (int j = 0; j < 8; ++j)
    __builtin_amdgcn_global_load_lds(
        (const __attribute__((address_space(1))) void*)(bg + j * 32),
        (__attribute__((address_space(3))) void*)(bs_b + j * 2048), 16, 0, 0);

  const unsigned short* ar0 = attn_bf + (size_t)(bm + wid * 32 + l16) * 256 + qd * 8;
  const unsigned short* ar1 = ar0 + 16 * 256;
  bf16x8 a0[8], a1[8];
#pragma unroll
  for (int j = 0; j < 8; ++j) {
    a0[j] = *(const bf16x8*)(ar0 + j * 32);
    a1[j] = *(const bf16x8*)(ar1 + j * 32);
  }
  __syncthreads();

  f32x4 acc[2][4] = {};
#pragma unroll
  for (int j = 0; j < 8; ++j) {
    const unsigned short* bt = Bs + j * 2048 + l16 * 32 + qd * 8;
#pragma unroll
    for (int ni = 0; ni < 4; ++ni) {
      const bf16x8 bf = *(const bf16x8*)(bt + ni * 512);
      acc[0][ni] = __builtin_amdgcn_mfma_f32_16x16x32_bf16(a0[j], bf, acc[0][ni], 0, 0, 0);
      acc[1][ni] = __builtin_amdgcn_mfma_f32_16x16x32_bf16(a1[j], bf, acc[1][ni], 0, 0, 0);
    }
  }
#pragma unroll
  for (int ni = 0; ni < 4; ++ni) {
    const int c = bn + ni * 16 + l16;
    const float bb = out_b[c];
#pragma unroll
    for (int mi = 0; mi < 2; ++mi)
#pragma unroll
      for (int rr = 0; rr < 4; ++rr) {
        const int gm = bm + wid * 32 + mi * 16 + qd * 4 + rr;
        out[(size_t)gm * 256 + c] = acc[mi][ni][rr] + bb;
      }
  }
}

extern "C" void kernel_launch(void* const* d_in, const int* in_sizes, int n_in,
                              void* d_out, int out_size, void* d_ws, size_t ws_size,
                              hipStream_t stream) {
  const float* query        = (const float*)d_in[0];
  const float* value        = (const float*)d_in[1];
  const float* refp         = (const float*)d_in[2];
  const float* value_proj_w = (const float*)d_in[3];
  const float* value_proj_b = (const float*)d_in[4];
  const float* offsets_w    = (const float*)d_in[5];
  const float* offsets_b    = (const float*)d_in[6];
  const float* attn_w_w     = (const float*)d_in[7];
  const float* attn_w_b     = (const float*)d_in[8];
  const float* out_w        = (const float*)d_in[9];
  const float* out_b        = (const float*)d_in[10];
  float* out = (float*)d_out;

  const int M = M_ROWS; // 21760
  const size_t SZ_V   = (size_t)M * 256 * 2; // 11.1 MB (== SZ_V_B)
  const size_t SZ_OFF = (size_t)M * 384 * 2; // 16.7 MB
  char* w = (char*)d_ws;
  unsigned short* value_bf = (unsigned short*)w;               // consumed by gemm12
  unsigned short* attn_bf  = (unsigned short*)w;               // aliases value_bf
  unsigned short* query_bf = (unsigned short*)(w + SZ_V);
  unsigned short* v_even   = (unsigned short*)(w + 2 * SZ_V);  // head-major natural
  unsigned short* v_odd    = (unsigned short*)(w + 3 * SZ_V);  // half-shifted pairs
  f16* offaw_h             = (f16*)(w + 3 * SZ_V + SZ_ODD_B);
  char* wts                = w + 3 * SZ_V + SZ_ODD_B + SZ_OFF;
  unsigned short* wt_vp    = (unsigned short*)wts;             // 256*256
  unsigned short* wt_q     = wt_vp + 65536;                    // 384*256
  unsigned short* wt_out   = wt_q + 98304;                     // 256*256
  float* biasq             = (float*)(wt_out + 65536);         // 384

  dim3 blk(256);
  const int n4 = M * 64;
  const int prep_blocks = (2 * n4 + 229760 + 255) / 256;
  prep_all<<<prep_blocks, blk, 0, stream>>>(
      value, query, value_bf, query_bf,
      value_proj_w, offsets_w, attn_w_w, out_w, offsets_b, attn_w_b,
      wt_vp, wt_q, wt_out, biasq, n4);
  // merged value-proj (bx 0-3, head-major bf16 v) + offsets/logits (bx 4-9, f16)
  gemm12_kernel<<<1700, blk, 0, stream>>>(
      value_bf, query_bf, wt_vp, wt_q, value_proj_b, biasq, v_even, offaw_h);
  // build half-shifted odd-pair copy (23 MB, L2-hot)
  dup_odd_kernel<<<2840, blk, 0, stream>>>(v_even, v_odd);
  // fused softmax + sampling (XCD-swizzled, full-line gather) -> bf16
  sample_fused_kernel<<<M / 8, blk, 0, stream>>>(v_even, refp, offaw_h, attn_bf);
  // output projection -> fp32 out
  gemm_out_kernel<<<680, blk, 0, stream>>>(attn_bf, wt_out, out_b, out);
}

// Round 4
// 171.796 us; speedup vs baseline: 1.0458x; 1.0458x over previous
//
#include <hip/hip_runtime.h>
#include <hip/hip_bf16.h>
#include <math.h>

// Problem constants
#define B_ 4
#define NQ 5440          // 64*64 + 32*32 + 16*16 + 8*8
#define M_ROWS (B_ * NQ) // 21760
#define NH 8
#define NL 4
#define NP 4
#define HD 32

typedef __attribute__((ext_vector_type(8))) short bf16x8; // 8 bf16 (4 VGPRs)
typedef __attribute__((ext_vector_type(4))) short bf16x4; // 8 bytes
typedef __attribute__((ext_vector_type(4))) float f32x4;
typedef _Float16 f16;

static __device__ __forceinline__ unsigned short f2bf(float f) {
  union { float f; unsigned u; } v; v.f = f;
  unsigned r = (v.u + 0x7fffu + ((v.u >> 16) & 1u)) >> 16; // RNE
  return (unsigned short)r;
}

// ---------------- merged prep: fp32->bf16 of value+query + weight transpose/convert
__global__ __launch_bounds__(256) void prep_all(
    const float* __restrict__ value, const float* __restrict__ query,
    unsigned short* __restrict__ value_bf, unsigned short* __restrict__ query_bf,
    const float* __restrict__ vpw, const float* __restrict__ offw,
    const float* __restrict__ attnw, const float* __restrict__ outw,
    const float* __restrict__ offb, const float* __restrict__ attnb,
    unsigned short* __restrict__ vp_t, unsigned short* __restrict__ q_t,
    unsigned short* __restrict__ out_t, float* __restrict__ biasq, int n4) {
  int id = blockIdx.x * 256 + threadIdx.x;
  if (id < 2 * n4) { // conversion part
    const float* src; unsigned short* dst; int j;
    if (id < n4) { src = value; dst = value_bf; j = id; }
    else { src = query; dst = query_bf; j = id - n4; }
    float4 f = ((const float4*)src)[j];
    bf16x4 o;
    o[0] = (short)f2bf(f.x); o[1] = (short)f2bf(f.y);
    o[2] = (short)f2bf(f.z); o[3] = (short)f2bf(f.w);
    ((bf16x4*)dst)[j] = o;
    return;
  }
  int w = id - 2 * n4;
  if (w < 65536) {                        // vp_t[256][256]
    int n = w >> 8, k = w & 255;
    vp_t[w] = f2bf(vpw[k * 256 + n]);
  } else if (w < 163840) {                // q_t[384][256] = [off^T ; attn^T]
    int q = w - 65536; int n = q >> 8, k = q & 255;
    q_t[q] = f2bf(n < 256 ? offw[k * 256 + n] : attnw[k * 128 + (n - 256)]);
  } else if (w < 229376) {                // out_t[256][256]
    int o = w - 163840; int n = o >> 8, k = o & 255;
    out_t[o] = f2bf(outw[k * 256 + n]);
  } else if (w < 229760) {                // biasq[384]
    int j = w - 229376;
    biasq[j] = j < 256 ? offb[j] : attnb[j - 256];
  }
}

// ---------------- GEMM1+2 merged: B-tile in LDS (1 barrier), ALL 16 A-fragments
// register-prefetched BEFORE the barrier. Block = 128 M x 64 N.
// Value-proj output is written as f16 (head-major) for the fma_mix gather.
__global__ __launch_bounds__(256) void gemm12_kernel(
    const unsigned short* __restrict__ valbf, const unsigned short* __restrict__ qrybf,
    const unsigned short* __restrict__ wt_vp, const unsigned short* __restrict__ wt_q,
    const float* __restrict__ vp_b, const float* __restrict__ biasq,
    f16* __restrict__ v_h, f16* __restrict__ offaw_h) {
  __shared__ unsigned short Bs[8 * 64 * 32]; // 32 KB: 8 k-tiles of [64 n][32 k]
  const int t = threadIdx.x;
  const int lane = t & 63, wid = t >> 6;
  const int qd = lane >> 4, l16 = lane & 15;
  const int g = blockIdx.x;
  const int grp = g / 80, r = g % 80;
  int by, bx;
  if (grp < 21) { by = grp * 8 + (r & 7); bx = r >> 3; }
  else          { by = 168 + (r & 1);     bx = r >> 1; } // tail: 2 rows x 10 cols
  const int bm = by * 128;
  const bool isv = bx < 4;
  const int bn = isv ? bx * 64 : (bx - 4) * 64;
  const unsigned short* A  = isv ? valbf : qrybf;
  const unsigned short* Wt = isv ? wt_vp : wt_q;

  // stage B tile (weights) via async global->LDS
  const unsigned short* bg = Wt + (size_t)(bn + (t >> 2)) * 256 + (t & 3) * 8;
  unsigned short* bs_b = Bs + (t & 192) * 8;
#pragma unroll
  for (int j = 0; j < 8; ++j)
    __builtin_amdgcn_global_load_lds(
        (const __attribute__((address_space(1))) void*)(bg + j * 32),
        (__attribute__((address_space(3))) void*)(bs_b + j * 2048), 16, 0, 0);

  // prefetch ALL A fragments into registers (16 independent dwordx4 loads)
  const unsigned short* ar0 = A + (size_t)(bm + wid * 32 + l16) * 256 + qd * 8;
  const unsigned short* ar1 = ar0 + 16 * 256;
  bf16x8 a0[8], a1[8];
#pragma unroll
  for (int j = 0; j < 8; ++j) {
    a0[j] = *(const bf16x8*)(ar0 + j * 32);
    a1[j] = *(const bf16x8*)(ar1 + j * 32);
  }
  __syncthreads(); // drains vmcnt: B staged AND A regs resident

  f32x4 acc[2][4] = {};
#pragma unroll
  for (int j = 0; j < 8; ++j) {
    const unsigned short* bt = Bs + j * 2048 + l16 * 32 + qd * 8;
#pragma unroll
    for (int ni = 0; ni < 4; ++ni) {
      const bf16x8 bf = *(const bf16x8*)(bt + ni * 512);
      acc[0][ni] = __builtin_amdgcn_mfma_f32_16x16x32_bf16(a0[j], bf, acc[0][ni], 0, 0, 0);
      acc[1][ni] = __builtin_amdgcn_mfma_f32_16x16x32_bf16(a1[j], bf, acc[1][ni], 0, 0, 0);
    }
  }
  // C/D layout: col = lane&15, row = (lane>>4)*4 + reg [m89-verified]
  if (isv) {
#pragma unroll
    for (int ni = 0; ni < 4; ++ni) {
      const int c = bn + ni * 16 + l16;
      const float bb = vp_b[c];
      const int h = c >> 5, d = c & 31;
#pragma unroll
      for (int mi = 0; mi < 2; ++mi)
#pragma unroll
        for (int rr = 0; rr < 4; ++rr) {
          const int gm = bm + wid * 32 + mi * 16 + qd * 4 + rr;
          const int b = gm / NQ, pix = gm - b * NQ;
          v_h[((size_t)(b * NH + h) * NQ + pix) * HD + d] = (f16)(acc[mi][ni][rr] + bb);
        }
    }
  } else {
#pragma unroll
    for (int ni = 0; ni < 4; ++ni) {
      const int c = bn + ni * 16 + l16;
      const float bb = biasq[c];
#pragma unroll
      for (int mi = 0; mi < 2; ++mi)
#pragma unroll
        for (int rr = 0; rr < 4; ++rr) {
          const int gm = bm + wid * 32 + mi * 16 + qd * 4 + rr;
          offaw_h[(size_t)gm * 384 + c] = (f16)(acc[mi][ni][rr] + bb);
        }
    }
  }
}

// ---------------- GEMM3: out = attn_bf @ out_w^T + out_b (fp32), same A-prefetch
__global__ __launch_bounds__(256) void gemm_out_kernel(
    const unsigned short* __restrict__ attn_bf, const unsigned short* __restrict__ wt_out,
    const float* __restrict__ out_b, float* __restrict__ out) {
  __shared__ unsigned short Bs[8 * 64 * 32];
  const int t = threadIdx.x;
  const int lane = t & 63, wid = t >> 6;
  const int qd = lane >> 4, l16 = lane & 15;
  const int g = blockIdx.x;
  const int grp = g / 32, r = g % 32;
  int by, bx;
  if (grp < 21) { by = grp * 8 + (r & 7); bx = r >> 3; }
  else          { by = 168 + (r & 1);     bx = r >> 1; }
  const int bm = by * 128, bn = bx * 64;

  const unsigned short* bg = wt_out + (size_t)(bn + (t >> 2)) * 256 + (t & 3) * 8;
  unsigned short* bs_b = Bs + (t & 192) * 8;
#pragma unroll
  for (int j = 0; j < 8; ++j)
    __builtin_amdgcn_global_load_lds(
        (const __attribute__((address_space(1))) void*)(bg + j * 32),
        (__attribute__((address_space(3))) void*)(bs_b + j * 2048), 16, 0, 0);

  const unsigned short* ar0 = attn_bf + (size_t)(bm + wid * 32 + l16) * 256 + qd * 8;
  const unsigned short* ar1 = ar0 + 16 * 256;
  bf16x8 a0[8], a1[8];
#pragma unroll
  for (int j = 0; j < 8; ++j) {
    a0[j] = *(const bf16x8*)(ar0 + j * 32);
    a1[j] = *(const bf16x8*)(ar1 + j * 32);
  }
  __syncthreads();

  f32x4 acc[2][4] = {};
#pragma unroll
  for (int j = 0; j < 8; ++j) {
    const unsigned short* bt = Bs + j * 2048 + l16 * 32 + qd * 8;
#pragma unroll
    for (int ni = 0; ni < 4; ++ni) {
      const bf16x8 bf = *(const bf16x8*)(bt + ni * 512);
      acc[0][ni] = __builtin_amdgcn_mfma_f32_16x16x32_bf16(a0[j], bf, acc[0][ni], 0, 0, 0);
      acc[1][ni] = __builtin_amdgcn_mfma_f32_16x16x32_bf16(a1[j], bf, acc[1][ni], 0, 0, 0);
    }
  }
#pragma unroll
  for (int ni = 0; ni < 4; ++ni) {
    const int c = bn + ni * 16 + l16;
    const float bb = out_b[c];
#pragma unroll
    for (int mi = 0; mi < 2; ++mi)
#pragma unroll
      for (int rr = 0; rr < 4; ++rr) {
        const int gm = bm + wid * 32 + mi * 16 + qd * 4 + rr;
        out[(size_t)gm * 256 + c] = acc[mi][ni][rr] + bb;
      }
  }
}

// ---------------- Fused softmax + deformable sampling (L2-resident layout,
// VALU-minimized gather):
//  - phase A precomputes FULL byte offsets (vbase+idx*64) and weights,
//    stored interleaved as uint2 [p][qh][c] -> phase B = 1 ds_read_b64
//    (contiguous 128 B per inst, conflict-free) + 1 dwordx4 + 8 fma_mix.
//  - v is f16: acc += w * (float)h compiles to v_fma_mix_f32 (no unpack ops).
__global__ __launch_bounds__(256) void sample_fused_kernel(
    const f16* __restrict__ v, const float* __restrict__ refp,
    const f16* __restrict__ offaw_h, unsigned short* __restrict__ out) {
  __shared__ __align__(16) uint2 s_t[16 * 64 * 4]; // 32 KB [p][qh][c] = (off, w)
  const int t = threadIdx.x;
  // XCD swizzle: xcd = blk&7, batch = xcd>>1 (per-batch v is 2.78 MB < 4 MB L2/XCD)
  const int blk = blockIdx.x;
  const int b = (blk & 7) >> 1;
  const int q0loc = ((blk >> 3) * 2 + (blk & 1)) * 8;
  const int q0 = b * NQ + q0loc;

  { // ---- phase A: load offsets+logits, in-wave softmax, tuple compute
    const int lane = t & 63, wave = t >> 6;
    const int qh = wave * 16 + (lane >> 2);     // 64 (q,h) pairs
    const int l = lane & 3;                     // level within 4-lane group
    const int q = qh >> 3, h = qh & 7;
    const f16* row = offaw_h + (size_t)(q0 + q) * 384;
    union { uint4 u4; f16 hh[8]; } off8;
    off8.u4 = *(const uint4*)(row + h * 32 + l * 8);
    union { uint2 u2; f16 hh[4]; } lg4;
    lg4.u2 = *(const uint2*)(row + 256 + h * 16 + l * 4);
    const float2 rxy = *(const float2*)(refp + (size_t)(q0 + q) * 8 + l * 2);

    // softmax over 16 logits spread 4-per-lane across the 4-lane group
    float lgf[4];
#pragma unroll
    for (int j = 0; j < 4; ++j) lgf[j] = (float)lg4.hh[j];
    float m = fmaxf(fmaxf(lgf[0], lgf[1]), fmaxf(lgf[2], lgf[3]));
    m = fmaxf(m, __shfl_xor(m, 1));
    m = fmaxf(m, __shfl_xor(m, 2));
    float e[4], s = 0.f;
#pragma unroll
    for (int j = 0; j < 4; ++j) { e[j] = __expf(lgf[j] - m); s += e[j]; }
    s += __shfl_xor(s, 1);
    s += __shfl_xor(s, 2);
    const float inv = 1.f / s;

    const int Wl = 64 >> l, Hl = 64 >> l;
    const int LVL_OFF = (l == 0) ? 0 : (l == 1) ? 4096 : (l == 2) ? 5120 : 5376;
    const unsigned vbase = (unsigned)(((b * NH + h) * NQ + LVL_OFF) * 64);
    const float pxb = rxy.x * (float)Wl - 0.5f;
    const float pyb = rxy.y * (float)Hl - 0.5f;
#pragma unroll
    for (int pp = 0; pp < 4; ++pp) {
      const int p = l * 4 + pp;
      const float ox = (float)off8.hh[pp * 2];
      const float oy = (float)off8.hh[pp * 2 + 1];
      const float a  = e[pp] * inv;
      const float px = pxb + ox;
      const float py = pyb + oy;
      const float x0f = floorf(px), y0f = floorf(py);
      const int x0 = (int)x0f, y0 = (int)y0f;
      const int x1 = x0 + 1, y1 = y0 + 1;
      const float wx = px - x0f, wy = py - y0f;
      const float m_x0 = (x0 >= 0 && x0 < Wl) ? 1.f : 0.f;
      const float m_x1 = (x1 >= 0 && x1 < Wl) ? 1.f : 0.f;
      const float m_y0 = (y0 >= 0 && y0 < Hl) ? 1.f : 0.f;
      const float m_y1 = (y1 >= 0 && y1 < Hl) ? 1.f : 0.f;
      const int cx0 = min(max(x0, 0), Wl - 1), cx1 = min(max(x1, 0), Wl - 1);
      const int cy0 = min(max(y0, 0), Hl - 1), cy1 = min(max(y1, 0), Hl - 1);
      const int ti = (p * 64 + qh) * 4;
      const unsigned o0 = vbase + (unsigned)((cy0 * Wl + cx0) * 64);
      const unsigned o1 = vbase + (unsigned)((cy0 * Wl + cx1) * 64);
      const unsigned o2 = vbase + (unsigned)((cy1 * Wl + cx0) * 64);
      const unsigned o3 = vbase + (unsigned)((cy1 * Wl + cx1) * 64);
      const float w0 = a * (1.f - wx) * (1.f - wy) * m_x0 * m_y0;
      const float w1 = a * wx * (1.f - wy) * m_x1 * m_y0;
      const float w2 = a * (1.f - wx) * wy * m_x0 * m_y1;
      const float w3 = a * wx * wy * m_x1 * m_y1;
      uint4 pk01, pk23;
      pk01.x = o0; pk01.y = __float_as_uint(w0);
      pk01.z = o1; pk01.w = __float_as_uint(w1);
      pk23.x = o2; pk23.y = __float_as_uint(w2);
      pk23.z = o3; pk23.w = __float_as_uint(w3);
      *(uint4*)&s_t[ti]     = pk01;
      *(uint4*)&s_t[ti + 2] = pk23;
    }
  }
  __syncthreads();
  // ---- phase B: gather. lane = qh_lo(2b) | corner(2b) | d8(2b)
  const int lane = t & 63, wave = t >> 6;
  const int qh_lo = lane >> 4;
  const int c     = (lane >> 2) & 3;
  const int d8    = lane & 3;
  const char* vL = (const char*)v + d8 * 16;  // 16 B sub-chunk of 64 B head vec

  for (int s = 0; s < 4; ++s) {
    const int tqh = wave * 16 + s * 4 + qh_lo;
    const int h = tqh & 7;
    float acc[8] = {};
#pragma unroll
    for (int p = 0; p < 16; ++p) {
      const uint2 tw = s_t[(p * 64 + tqh) * 4 + c];
      const float w = __uint_as_float(tw.y);
      union { uint4 u4; f16 hh[8]; } cc;
      cc.u4 = *(const uint4*)(vL + tw.x);
#pragma unroll
      for (int k = 0; k < 8; ++k)
        acc[k] += w * (float)cc.hh[k];   // v_fma_mix_f32
    }
    // combine the 4 corner partials (lanes differing in bits 2-3)
#pragma unroll
    for (int k = 0; k < 8; ++k) {
      acc[k] += __shfl_xor(acc[k], 4);
      acc[k] += __shfl_xor(acc[k], 8);
    }
    if (c == 0) {
      const int q = tqh >> 3;
      bf16x8 ov;
#pragma unroll
      for (int k = 0; k < 8; ++k) ov[k] = (short)f2bf(acc[k]);
      *(bf16x8*)(out + (size_t)(q0 + q) * 256 + h * HD + d8 * 8) = ov;
    }
  }
}

extern "C" void kernel_launch(void* const* d_in, const int* in_sizes, int n_in,
                              void* d_out, int out_size, void* d_ws, size_t ws_size,
                              hipStream_t stream) {
  const float* query        = (const float*)d_in[0];
  const float* value        = (const float*)d_in[1];
  const float* refp         = (const float*)d_in[2];
  const float* value_proj_w = (const float*)d_in[3];
  const float* value_proj_b = (const float*)d_in[4];
  const float* offsets_w    = (const float*)d_in[5];
  const float* offsets_b    = (const float*)d_in[6];
  const float* attn_w_w     = (const float*)d_in[7];
  const float* attn_w_b     = (const float*)d_in[8];
  const float* out_w        = (const float*)d_in[9];
  const float* out_b        = (const float*)d_in[10];
  float* out = (float*)d_out;

  const int M = M_ROWS; // 21760
  const size_t SZ_V   = (size_t)M * 256 * 2; // 11.1 MB
  const size_t SZ_OFF = (size_t)M * 384 * 2; // 16.7 MB
  char* w = (char*)d_ws;
  unsigned short* value_bf = (unsigned short*)w;               // consumed by gemm12
  unsigned short* attn_bf  = (unsigned short*)w;               // aliases value_bf
  unsigned short* query_bf = (unsigned short*)(w + SZ_V);
  f16* v_h                 = (f16*)(w + 2 * SZ_V);             // head-major f16
  f16* offaw_h             = (f16*)(w + 3 * SZ_V);
  char* wts                = w + 3 * SZ_V + SZ_OFF;
  unsigned short* wt_vp    = (unsigned short*)wts;             // 256*256
  unsigned short* wt_q     = wt_vp + 65536;                    // 384*256
  unsigned short* wt_out   = wt_q + 98304;                     // 256*256
  float* biasq             = (float*)(wt_out + 65536);         // 384

  dim3 blk(256);
  const int n4 = M * 64;
  const int prep_blocks = (2 * n4 + 229760 + 255) / 256;
  prep_all<<<prep_blocks, blk, 0, stream>>>(
      value, query, value_bf, query_bf,
      value_proj_w, offsets_w, attn_w_w, out_w, offsets_b, attn_w_b,
      wt_vp, wt_q, wt_out, biasq, n4);
  // merged value-proj (bx 0-3, head-major f16 v) + offsets/logits (bx 4-9, f16)
  gemm12_kernel<<<1700, blk, 0, stream>>>(
      value_bf, query_bf, wt_vp, wt_q, value_proj_b, biasq, v_h, offaw_h);
  // fused softmax + sampling (XCD-swizzled) -> bf16
  sample_fused_kernel<<<M / 8, blk, 0, stream>>>(v_h, refp, offaw_h, attn_bf);
  // output projection -> fp32 out
  gemm_out_kernel<<<680, blk, 0, stream>>>(attn_bf, wt_out, out_b, out);
}